// Round 5
// baseline (666.537 us; speedup 1.0000x reference)
//
#include <hip/hip_runtime.h>
#include <cmath>

#define N_TOK 196
#define NPX   38416
#define CDIM  256

typedef _Float16 f16;
typedef __attribute__((ext_vector_type(8))) _Float16 half8;
typedef __attribute__((ext_vector_type(4))) float f32x4;

// ---------------------------------------------------------------------------
// Projection GEMM, split-K. M=1568, N=256, K=2048 split 8 ways. grid (4,25,8).
// ---------------------------------------------------------------------------
__global__ __launch_bounds__(256) void gemm_splitk(
    const float* __restrict__ A, const float* __restrict__ B,
    float* __restrict__ P)
{
    __shared__ float As[16][68];
    __shared__ float Bs[16][68];
    int tid = threadIdx.x;
    int tx = tid & 15, ty = tid >> 4;
    int m0 = blockIdx.y * 64, n0 = blockIdx.x * 64;
    int kz = blockIdx.z;
    float acc[4][4] = {};
    for (int k0 = kz * 256; k0 < kz * 256 + 256; k0 += 16) {
        __syncthreads();
        for (int e = tid; e < 1024; e += 256) {
            int m = e >> 4, kk = e & 15;
            int gm = m0 + m;
            As[kk][m] = (gm < 1568) ? A[(size_t)gm * 2048 + k0 + kk] : 0.f;
        }
        for (int e = tid; e < 1024; e += 256) {
            int kk = e >> 6, n = e & 63;
            Bs[kk][n] = B[(size_t)(k0 + kk) * 256 + n0 + n];
        }
        __syncthreads();
        #pragma unroll
        for (int kk = 0; kk < 16; ++kk) {
            float4 av = *(const float4*)&As[kk][ty * 4];
            float4 bv = *(const float4*)&Bs[kk][tx * 4];
            float a[4] = {av.x, av.y, av.z, av.w};
            float b[4] = {bv.x, bv.y, bv.z, bv.w};
            #pragma unroll
            for (int u = 0; u < 4; ++u)
                #pragma unroll
                for (int v = 0; v < 4; ++v) acc[u][v] += a[u] * b[v];
        }
    }
    float* Pz = P + (size_t)kz * 401408;
    #pragma unroll
    for (int u = 0; u < 4; ++u) {
        int gm = m0 + ty * 4 + u;
        if (gm >= 1568) continue;
        #pragma unroll
        for (int v = 0; v < 4; ++v) {
            int gn = n0 + tx * 4 + v;
            Pz[(size_t)gm * 256 + gn] = acc[u][v];
        }
    }
}

// sum 8 K-slices + bias -> fp16 sub
__global__ void reduce_subh(const float* __restrict__ P,
                            const float* __restrict__ bias,
                            f16* __restrict__ subh)
{
    int e = blockIdx.x * 256 + threadIdx.x;
    if (e >= 401408) return;
    float s = bias[e & 255];
    #pragma unroll
    for (int z = 0; z < 8; ++z) s += P[(size_t)z * 401408 + e];
    subh[e] = (f16)s;
}

// ---------------------------------------------------------------------------
// w [tap][Kc][D] fp32 -> wt [tap][D][Kc] fp16  (tap=1 gives plain transpose)
// ---------------------------------------------------------------------------
__global__ void cvt_wt(const float* __restrict__ w, f16* __restrict__ wt,
                       int Kc, int D, int total)
{
    int e = blockIdx.x * 256 + threadIdx.x;
    if (e >= total) return;
    int td = Kc * D;
    int tap = e / td, r = e - tap * td;
    int c = r / D, d = r - c * D;
    wt[(size_t)(tap * D + d) * Kc + c] = (f16)w[e];
}

// x [b][196][2048] fp32 -> xht [b][2048][200] fp16 (k-pad 200, zeros)
__global__ __launch_bounds__(256) void cvt_xT(const float* __restrict__ x,
                                              f16* __restrict__ xht)
{
    __shared__ float t[32][33];
    int b = blockIdx.z;
    int i0 = blockIdx.y * 32, n0 = blockIdx.x * 32;
    const float* xb = x + (size_t)b * 196 * 2048;
    for (int e = threadIdx.x; e < 1024; e += 256) {
        int r = e >> 5, c = e & 31;
        int gi = i0 + r;
        t[r][c] = (gi < 196) ? xb[(size_t)gi * 2048 + n0 + c] : 0.f;
    }
    __syncthreads();
    f16* xb2 = xht + (size_t)b * 2048 * 200;
    for (int e = threadIdx.x; e < 1024; e += 256) {
        int nl = e >> 5, il = e & 31;
        int gi = i0 + il, gn = n0 + nl;
        if (gi < 200) xb2[(size_t)gn * 200 + gi] = (f16)t[il][nl];
    }
}

// ---------------------------------------------------------------------------
// Conv1 v3: barrier-free K-loop. Block tile 256px (8i x 32j) x 128d, 4 waves.
// Wave = 128px (4i) x 64d, acc 8x4 f32x4 (128 AGPR). A (sub rows) staged once
// in LDS; B (weights) streamed from global (L2-resident, per-tap reg dbuf).
// grid (7, 25, 8).
// ---------------------------------------------------------------------------
__global__ __launch_bounds__(256, 2) void conv1_mfma(
    const f16* __restrict__ sub_h,   // [8][196][256]
    const f16* __restrict__ w1t,     // [9][128][256]
    const float* __restrict__ b1,    // [128]
    f16* __restrict__ Y1h)           // [8][196][196][128]
{
    __shared__ f16 sh[17408];        // 34816 B
    f16* SJ = sh;                    // [34][264] rows j0-1..j0+32
    f16* SI = sh + 8976;             // [10][264] rows i0-1..i0+8
    f16* OT = sh;                    // epilogue [128][136] (aliases SJ/SI)

    int b = blockIdx.z;
    int i0 = blockIdx.y * 8, j0 = blockIdx.x * 32;
    int tid = threadIdx.x;
    const f16* subB = sub_h + (size_t)b * N_TOK * CDIM;

    uint4 zz = make_uint4(0, 0, 0, 0);
    for (int e = tid; e < 1088; e += 256) {       // SJ
        int r = e >> 5, q = e & 31;
        int gj = j0 - 1 + r;
        uint4 v = zz;
        if (gj >= 0 && gj < N_TOK) v = *(const uint4*)(subB + gj * CDIM + q * 8);
        *(uint4*)(SJ + r * 264 + q * 8) = v;
    }
    for (int e = tid; e < 320; e += 256) {        // SI
        int r = e >> 5, q = e & 31;
        int gi = i0 - 1 + r;
        uint4 v = zz;
        if (gi >= 0 && gi < N_TOK) v = *(const uint4*)(subB + gi * CDIM + q * 8);
        *(uint4*)(SI + r * 264 + q * 8) = v;
    }
    __syncthreads();

    int wave = tid >> 6, lane = tid & 63;
    int quad = lane >> 4, l16 = lane & 15;
    int p  = wave >> 1;          // px half: i base = p*4
    int dh = wave & 1;           // d half: d0 = dh*64
    int d0 = dh * 64;

    float bias_r[4];
    #pragma unroll
    for (int n = 0; n < 4; ++n) bias_r[n] = b1[d0 + n * 16 + l16];

    // per-lane weight base: row = d0 + l16 (+n*16 +tap*128), col = c0 + quad*8
    const f16* wb = w1t + (size_t)(d0 + l16) * 256 + quad * 8;

    f32x4 zero = {0.f, 0.f, 0.f, 0.f};
    f32x4 acc[8][4];
    #pragma unroll
    for (int m = 0; m < 8; ++m)
        #pragma unroll
        for (int n = 0; n < 4; ++n) acc[m][n] = zero;

    for (int c0 = 0; c0 < 256; c0 += 32) {
        // A-side: 6 SI rows + 6 SJ rows into registers (LDS, no barrier)
        half8 si[6];
        #pragma unroll
        for (int r = 0; r < 6; ++r)
            si[r] = *(const half8*)(SI + (p * 4 + r) * 264 + c0 + quad * 8);
        half8 sj[2][3];
        #pragma unroll
        for (int jf = 0; jf < 2; ++jf)
            #pragma unroll
            for (int dd = 0; dd < 3; ++dd)
                sj[jf][dd] = *(const half8*)(SJ + (jf * 16 + l16 + dd) * 264 + c0 + quad * 8);

        // B-side: per-tap register double-buffer from global (L2-hit)
        half8 bf[2][4];
        #pragma unroll
        for (int n = 0; n < 4; ++n)
            bf[0][n] = *(const half8*)(wb + (size_t)(n * 16) * 256 + c0);

        #pragma unroll
        for (int tap = 0; tap < 9; ++tap) {
            int cur = tap & 1;
            if (tap < 8) {
                int nxt = cur ^ 1;
                #pragma unroll
                for (int n = 0; n < 4; ++n)
                    bf[nxt][n] = *(const half8*)(wb + (size_t)((tap + 1) * 128 + n * 16) * 256 + c0);
            }
            int di = tap / 3, dj = tap % 3;
            #pragma unroll
            for (int i = 0; i < 4; ++i) {
                half8 sb = si[i + di];
                half8 a0 = sb * sj[0][dj];
                half8 a1 = sb * sj[1][dj];
                #pragma unroll
                for (int n = 0; n < 4; ++n) {
                    acc[i * 2 + 0][n] = __builtin_amdgcn_mfma_f32_16x16x32_f16(a0, bf[cur][n], acc[i * 2 + 0][n], 0, 0, 0);
                    acc[i * 2 + 1][n] = __builtin_amdgcn_mfma_f32_16x16x32_f16(a1, bf[cur][n], acc[i * 2 + 1][n], 0, 0, 0);
                }
            }
        }
    }

    // epilogue: two px-half phases through OT (aliases SJ/SI)
    __syncthreads();
    f16* Yb = Y1h + (size_t)b * NPX * 128;
    #pragma unroll
    for (int ph = 0; ph < 2; ++ph) {
        if (p == ph) {
            #pragma unroll
            for (int i = 0; i < 4; ++i)
                #pragma unroll
                for (int jf = 0; jf < 2; ++jf) {
                    int m = i * 2 + jf;
                    #pragma unroll
                    for (int n = 0; n < 4; ++n) {
                        int dl = d0 + n * 16 + l16;
                        #pragma unroll
                        for (int r = 0; r < 4; ++r) {
                            int pxl = i * 32 + jf * 16 + quad * 4 + r;
                            OT[pxl * 136 + dl] = (f16)fmaxf(acc[m][n][r] + bias_r[n], 0.f);
                        }
                    }
                }
        }
        __syncthreads();
        for (int e = tid; e < 2048; e += 256) {
            int pxl = e >> 4, q = e & 15;
            int gi = i0 + ph * 4 + (pxl >> 5), gj = j0 + (pxl & 31);
            if (gi < N_TOK && gj < N_TOK)
                *(uint4*)(Yb + ((size_t)gi * N_TOK + gj) * 128 + q * 8) =
                    *(const uint4*)(OT + pxl * 136 + q * 8);
        }
        __syncthreads();
    }
}

// ---------------------------------------------------------------------------
// Conv2 MFMA: 3x3 dil (1,2), 128->64, fp16 in/out.
// ---------------------------------------------------------------------------
__global__ __launch_bounds__(256, 2) void conv2_mfma(
    const f16* __restrict__ Y1h, const f16* __restrict__ w2t,
    const float* __restrict__ b2, f16* __restrict__ Y2h)
{
    __shared__ f16 sh[22144];
    f16* Ys = sh;                    // [4][36][136]
    f16* BW = sh + 19584;            // [64][40]
    f16* OT = sh;                    // epilogue [64][72]

    int b = blockIdx.z;
    int i0 = blockIdx.y * 2, j0 = blockIdx.x * 32;
    int tid = threadIdx.x;
    const f16* Yb = Y1h + (size_t)b * NPX * 128;

    uint4 zz = make_uint4(0, 0, 0, 0);
    for (int e = tid; e < 2304; e += 256) {
        int ir = e / 576, rem = e - ir * 576;
        int jq = rem >> 4, q = rem & 15;
        int gi = i0 - 1 + ir, gj = j0 - 2 + jq;
        uint4 v = zz;
        if (gi >= 0 && gi < N_TOK && gj >= 0 && gj < N_TOK)
            v = *(const uint4*)(Yb + ((size_t)gi * N_TOK + gj) * 128 + q * 8);
        *(uint4*)(Ys + (ir * 36 + jq) * 136 + q * 8) = v;
    }

    int wave = tid >> 6, lane = tid & 63;
    int quad = lane >> 4, l16 = lane & 15;
    int ii = wave >> 1, jb = (wave & 1) * 16;

    f32x4 zero = {0.f, 0.f, 0.f, 0.f};
    f32x4 acc[4] = {zero, zero, zero, zero};

    for (int tap = 0; tap < 9; ++tap) {
        int di = tap / 3 - 1, dj2 = (tap % 3 - 1) * 2;
        for (int c0 = 0; c0 < 128; c0 += 32) {
            __syncthreads();
            {
                int d = tid >> 2, q = tid & 3;
                *(uint4*)(BW + d * 40 + q * 8) =
                    *(const uint4*)(w2t + (size_t)(tap * 64 + d) * 128 + c0 + q * 8);
            }
            __syncthreads();
            half8 a = *(const half8*)(Ys + ((ii + di + 1) * 36 + jb + l16 + dj2 + 2) * 136
                                      + c0 + quad * 8);
            #pragma unroll
            for (int n = 0; n < 4; ++n) {
                half8 bf = *(const half8*)(BW + (n * 16 + l16) * 40 + quad * 8);
                acc[n] = __builtin_amdgcn_mfma_f32_16x16x32_f16(a, bf, acc[n], 0, 0, 0);
            }
        }
    }
    __syncthreads();
    #pragma unroll
    for (int n = 0; n < 4; ++n) {
        int d = n * 16 + l16;
        float bias = b2[d];
        #pragma unroll
        for (int r = 0; r < 4; ++r) {
            int px = ii * 32 + jb + quad * 4 + r;
            OT[px * 72 + d] = (f16)fmaxf(acc[n][r] + bias, 0.f);
        }
    }
    __syncthreads();
    f16* Zb = Y2h + (size_t)b * NPX * 64;
    for (int e = tid; e < 512; e += 256) {
        int px = e >> 3, q = e & 7;
        int i = i0 + (px >> 5), j = j0 + (px & 31);
        if (j < N_TOK)
            *(uint4*)(Zb + ((size_t)i * N_TOK + j) * 64 + q * 8) =
                *(const uint4*)(OT + px * 72 + q * 8);
    }
}

// ---------------------------------------------------------------------------
// Conv3: 3x3 dil (1,4), 64->1, fp16 input, fp32 accumulate -> X1 logits.
// ---------------------------------------------------------------------------
__global__ __launch_bounds__(256) void conv3_h(
    const f16* __restrict__ Y2h, const float* __restrict__ w3,
    const float* __restrict__ b3, float* __restrict__ X1)
{
    __shared__ float w[576];
    int b = blockIdx.y;
    const f16* Yb = Y2h + (size_t)b * NPX * 64;
    for (int e = threadIdx.x; e < 576; e += 256) w[e] = w3[e];
    __syncthreads();
    int px = blockIdx.x * 256 + threadIdx.x;
    if (px >= NPX) return;
    int i = px / 196, j = px - i * 196;
    float s = b3[0];
    for (int tap = 0; tap < 9; ++tap) {
        int gi = i + tap / 3 - 1, gj = j + (tap % 3 - 1) * 4;
        if (gi < 0 || gi >= N_TOK || gj < 0 || gj >= N_TOK) continue;
        const half8* src = (const half8*)(Yb + ((size_t)gi * N_TOK + gj) * 64);
        const float* wt = w + tap * 64;
        #pragma unroll
        for (int q = 0; q < 8; ++q) {
            half8 h = src[q];
            #pragma unroll
            for (int e = 0; e < 8; ++e) s += (float)h[e] * wt[q * 8 + e];
        }
    }
    X1[(size_t)b * NPX + px] = fmaxf(s, 0.f);
}

// ---------------------------------------------------------------------------
// Branch 0 MFMA: pair -> 1x1 stack 256->128->64->1, all in one block.
// ---------------------------------------------------------------------------
__global__ __launch_bounds__(256, 2) void branch0_mfma(
    const f16* __restrict__ sub_h,
    const f16* __restrict__ w01t,    // [128][256]
    const float* __restrict__ b01,
    const f16* __restrict__ w02t,    // [64][128]
    const float* __restrict__ b02,
    const float* __restrict__ w03, const float* __restrict__ b03,
    float* __restrict__ X0)
{
    __shared__ f16 sh[32000];
    __shared__ float W3s[64];
    f16* SJ = sh;            // [32][264]
    f16* SI = sh + 8448;     // [4][256]
    f16* BW = sh + 9472;     // [128][40]
    f16* H1 = sh + 14592;    // [128][136]
    f16* H2 = sh;            // [128][72] (aliases SJ/SI)

    int b = blockIdx.z;
    int i0 = blockIdx.y * 4, j0 = blockIdx.x * 32;
    int tid = threadIdx.x;
    const f16* subB = sub_h + (size_t)b * N_TOK * CDIM;

    uint4 zz = make_uint4(0, 0, 0, 0);
    for (int e = tid; e < 1024; e += 256) {
        int r = e >> 5, q = e & 31;
        int gj = j0 + r;
        uint4 v = zz;
        if (gj < N_TOK) v = *(const uint4*)(subB + gj * CDIM + q * 8);
        *(uint4*)(SJ + r * 264 + q * 8) = v;
    }
    if (tid < 128) {
        int r = tid >> 5, q = tid & 31;
        int gi = i0 + r;
        uint4 v = zz;
        if (gi < N_TOK) v = *(const uint4*)(subB + gi * CDIM + q * 8);
        *(uint4*)(SI + r * 256 + q * 8) = v;
    }
    if (tid < 64) W3s[tid] = w03[tid];

    int wave = tid >> 6, lane = tid & 63;
    int quad = lane >> 4, l16 = lane & 15;
    int ii = wave;

    f32x4 zero = {0.f, 0.f, 0.f, 0.f};
    f32x4 acc[2][8];
    #pragma unroll
    for (int t = 0; t < 2; ++t)
        #pragma unroll
        for (int n = 0; n < 8; ++n) acc[t][n] = zero;

    for (int c0 = 0; c0 < 256; c0 += 32) {
        __syncthreads();
        for (int e = tid; e < 512; e += 256) {
            int d = e >> 2, q = e & 3;
            *(uint4*)(BW + d * 40 + q * 8) =
                *(const uint4*)(w01t + (size_t)d * 256 + c0 + q * 8);
        }
        __syncthreads();
        half8 sib = *(const half8*)(SI + ii * 256 + c0 + quad * 8);
        half8 a0 = sib * *(const half8*)(SJ + l16 * 264 + c0 + quad * 8);
        half8 a1 = sib * *(const half8*)(SJ + (l16 + 16) * 264 + c0 + quad * 8);
        #pragma unroll
        for (int n = 0; n < 8; ++n) {
            half8 bf = *(const half8*)(BW + (n * 16 + l16) * 40 + quad * 8);
            acc[0][n] = __builtin_amdgcn_mfma_f32_16x16x32_f16(a0, bf, acc[0][n], 0, 0, 0);
            acc[1][n] = __builtin_amdgcn_mfma_f32_16x16x32_f16(a1, bf, acc[1][n], 0, 0, 0);
        }
    }
    #pragma unroll
    for (int t = 0; t < 2; ++t)
        #pragma unroll
        for (int n = 0; n < 8; ++n) {
            int d = n * 16 + l16;
            float bias = b01[d];
            #pragma unroll
            for (int r = 0; r < 4; ++r) {
                int px = ii * 32 + t * 16 + quad * 4 + r;
                H1[px * 136 + d] = (f16)fmaxf(acc[t][n][r] + bias, 0.f);
            }
        }

    f32x4 acc2[2][4];
    #pragma unroll
    for (int t = 0; t < 2; ++t)
        #pragma unroll
        for (int n = 0; n < 4; ++n) acc2[t][n] = zero;

    for (int c0 = 0; c0 < 128; c0 += 32) {
        __syncthreads();
        {
            int d = tid >> 2, q = tid & 3;
            if (d < 64)
                *(uint4*)(BW + d * 40 + q * 8) =
                    *(const uint4*)(w02t + (size_t)d * 128 + c0 + q * 8);
        }
        __syncthreads();
        half8 a0 = *(const half8*)(H1 + (ii * 32 + l16) * 136 + c0 + quad * 8);
        half8 a1 = *(const half8*)(H1 + (ii * 32 + 16 + l16) * 136 + c0 + quad * 8);
        #pragma unroll
        for (int n = 0; n < 4; ++n) {
            half8 bf = *(const half8*)(BW + (n * 16 + l16) * 40 + quad * 8);
            acc2[0][n] = __builtin_amdgcn_mfma_f32_16x16x32_f16(a0, bf, acc2[0][n], 0, 0, 0);
            acc2[1][n] = __builtin_amdgcn_mfma_f32_16x16x32_f16(a1, bf, acc2[1][n], 0, 0, 0);
        }
    }
    #pragma unroll
    for (int t = 0; t < 2; ++t)
        #pragma unroll
        for (int n = 0; n < 4; ++n) {
            int e = n * 16 + l16;
            float bias = b02[e];
            #pragma unroll
            for (int r = 0; r < 4; ++r) {
                int px = ii * 32 + t * 16 + quad * 4 + r;
                H2[px * 72 + e] = (f16)fmaxf(acc2[t][n][r] + bias, 0.f);
            }
        }
    __syncthreads();
    if (tid < 128) {
        int px = tid;
        float s = b03[0];
        const f16* h = H2 + px * 72;
        #pragma unroll 8
        for (int c = 0; c < 64; ++c) s += (float)h[c] * W3s[c];
        int i = i0 + (px >> 5), j = j0 + (px & 31);
        if (j < N_TOK)
            X0[(size_t)b * NPX + i * N_TOK + j] = fmaxf(s, 0.f);
    }
}

// ---------------------------------------------------------------------------
// Symmetrize + softmax over 38416 logits, /2 folded in.
// ---------------------------------------------------------------------------
__global__ __launch_bounds__(1024) void symsoftmax(float* __restrict__ X0,
                                                   float* __restrict__ X1)
{
    __shared__ float red[32];
    __shared__ float red2[32];
    float* X = (blockIdx.y ? X1 : X0) + (long long)blockIdx.x * NPX;
    int tid = threadIdx.x;
    float v[38];
    float mx = -3.0e38f;
    #pragma unroll
    for (int p = 0; p < 38; ++p) {
        int e = tid + p * 1024;
        if (e < NPX) {
            int i = e / 196, j = e - i * 196;
            float t = X[e] + X[j * 196 + i];
            v[p] = t;
            mx = fmaxf(mx, t);
        } else v[p] = -3.0e38f;
    }
    #pragma unroll
    for (int off = 32; off > 0; off >>= 1) mx = fmaxf(mx, __shfl_xor(mx, off));
    if ((tid & 63) == 0) red[tid >> 6] = mx;
    __syncthreads();
    if (tid < 64) {
        float m = (tid < 16) ? red[tid] : -3.0e38f;
        #pragma unroll
        for (int off = 8; off > 0; off >>= 1) m = fmaxf(m, __shfl_xor(m, off));
        if (tid == 0) red[0] = m;
    }
    __syncthreads();
    mx = red[0];
    float s = 0.f;
    #pragma unroll
    for (int p = 0; p < 38; ++p) {
        int e = tid + p * 1024;
        float ex = (e < NPX) ? expf(v[p] - mx) : 0.f;
        v[p] = ex;
        s += ex;
    }
    #pragma unroll
    for (int off = 32; off > 0; off >>= 1) s += __shfl_xor(s, off);
    if ((tid & 63) == 0) red2[tid >> 6] = s;
    __syncthreads();
    if (tid < 64) {
        float m = (tid < 16) ? red2[tid] : 0.f;
        #pragma unroll
        for (int off = 8; off > 0; off >>= 1) m += __shfl_xor(m, off);
        if (tid == 0) red2[0] = m;
    }
    __syncthreads();
    float scale = 0.5f / red2[0];
    #pragma unroll
    for (int p = 0; p < 38; ++p) {
        int e = tid + p * 1024;
        if (e < NPX) X[e] = v[p] * scale;
    }
}

// Ph[b][i][200] = fp16( (X0+X1) * 512 ), row-padded with zeros
__global__ void combine_ph(const float* __restrict__ X0,
                           const float* __restrict__ X1,
                           f16* __restrict__ Ph)
{
    int e = blockIdx.x * 256 + threadIdx.x;
    if (e >= 8 * 196 * 200) return;
    int j = e % 200;
    int row = e / 200;
    f16 v = (f16)0.f;
    if (j < 196) {
        int src = row * 196 + j;
        v = (f16)((X0[src] + X1[src]) * 512.0f);
    }
    Ph[e] = v;
}

// ---------------------------------------------------------------------------
// out[b] = (Ph[b]/512) @ x[b] via fp16 MFMA. grid (16, 4, 8).
// ---------------------------------------------------------------------------
__global__ __launch_bounds__(256, 2) void gemm_out(
    const f16* __restrict__ Ph, const f16* __restrict__ xht,
    float* __restrict__ out)
{
    __shared__ f16 As[64 * 72];
    __shared__ f16 Bs[128 * 72];
    int b = blockIdx.z;
    int n0 = blockIdx.x * 128, m0 = blockIdx.y * 64;
    int tid = threadIdx.x;
    const f16* Pb = Ph + (size_t)b * 196 * 200;
    const f16* xb = xht + (size_t)b * 2048 * 200;

    int wave = tid >> 6, lane = tid & 63;
    int quad = lane >> 4, l16 = lane & 15;

    f32x4 zero = {0.f, 0.f, 0.f, 0.f};
    f32x4 acc[8];
    #pragma unroll
    for (int n = 0; n < 8; ++n) acc[n] = zero;

    uint4 zz = make_uint4(0, 0, 0, 0);
    for (int k0 = 0; k0 < 256; k0 += 64) {
        __syncthreads();
        for (int e = tid; e < 512; e += 256) {
            int r = e >> 3, q = e & 7;
            int gm = m0 + r, k = k0 + q * 8;
            uint4 v = zz;
            if (gm < 196 && k < 200) v = *(const uint4*)(Pb + (size_t)gm * 200 + k);
            *(uint4*)(As + r * 72 + q * 8) = v;
        }
        for (int e = tid; e < 1024; e += 256) {
            int r = e >> 3, q = e & 7;
            int k = k0 + q * 8;
            uint4 v = zz;
            if (k < 200) v = *(const uint4*)(xb + (size_t)(n0 + r) * 200 + k);
            *(uint4*)(Bs + r * 72 + q * 8) = v;
        }
        __syncthreads();
        #pragma unroll
        for (int ks = 0; ks < 2; ++ks) {
            half8 a = *(const half8*)(As + (wave * 16 + l16) * 72 + ks * 32 + quad * 8);
            #pragma unroll
            for (int n = 0; n < 8; ++n) {
                half8 bf = *(const half8*)(Bs + (n * 16 + l16) * 72 + ks * 32 + quad * 8);
                acc[n] = __builtin_amdgcn_mfma_f32_16x16x32_f16(a, bf, acc[n], 0, 0, 0);
            }
        }
    }
    int m_base = m0 + wave * 16 + quad * 4;
    float* ob = out + (size_t)b * 196 * 2048;
    #pragma unroll
    for (int n = 0; n < 8; ++n) {
        int gn = n0 + n * 16 + l16;
        #pragma unroll
        for (int r = 0; r < 4; ++r) {
            int gm = m_base + r;
            if (gm < 196) ob[(size_t)gm * 2048 + gn] = acc[n][r] * (1.0f / 512.0f);
        }
    }
}

// ---------------------------------------------------------------------------
extern "C" void kernel_launch(void* const* d_in, const int* in_sizes, int n_in,
                              void* d_out, int out_size, void* d_ws, size_t ws_size,
                              hipStream_t stream)
{
    (void)in_sizes; (void)n_in; (void)out_size; (void)ws_size;
    const float* x     = (const float*)d_in[0];
    const float* w_prj = (const float*)d_in[1];
    const float* b_prj = (const float*)d_in[2];
    const float* w01   = (const float*)d_in[3];
    const float* b01   = (const float*)d_in[4];
    const float* w02   = (const float*)d_in[5];
    const float* b02   = (const float*)d_in[6];
    const float* w03   = (const float*)d_in[7];
    const float* b03   = (const float*)d_in[8];
    const float* w1    = (const float*)d_in[9];
    const float* b1    = (const float*)d_in[10];
    const float* w2    = (const float*)d_in[11];
    const float* b2    = (const float*)d_in[12];
    const float* w3    = (const float*)d_in[13];
    const float* b3    = (const float*)d_in[14];

    char* W = (char*)d_ws;
    float* part = (float*)(W + 0);          // 8*401408 f = 12.85 MB
    float* X0   = (float*)(W + 12845056);   // 307328 f
    float* X1   = (float*)(W + 14074368);   // 307328 f
    f16*   subh = (f16*)(W + 15303680);     // 401408 h
    f16*   w1t  = (f16*)(W + 16106496);     // 294912 h
    f16*   w2t  = (f16*)(W + 16696320);     // 73728 h
    f16*   w01t = (f16*)(W + 16843776);     // 32768 h
    f16*   w02t = (f16*)(W + 16909312);     // 8192 h
    f16*   Ph   = (f16*)(W + 16925696);     // 8*196*200 h
    f16*   xht  = (f16*)(W + 17552896);     // 8*2048*200 h
    f16*   Y1h  = (f16*)(W + 24106496);     // 8*38416*128 h = 78.7 MB
    f16*   Y2h  = (f16*)(W + 102782464);    // 8*38416*64 h  = 39.3 MB

    // 1. projection: split-K gemm -> partials -> reduce -> subh (fp16)
    gemm_splitk<<<dim3(4, 25, 8), 256, 0, stream>>>(x, w_prj, part);
    reduce_subh<<<dim3(1568), 256, 0, stream>>>(part, b_prj, subh);

    // 2. weight conversions + x transpose
    cvt_wt<<<dim3(1152), 256, 0, stream>>>(w1, w1t, 256, 128, 294912);
    cvt_wt<<<dim3(288),  256, 0, stream>>>(w2, w2t, 128, 64, 73728);
    cvt_wt<<<dim3(128),  256, 0, stream>>>(w01, w01t, 256, 128, 32768);
    cvt_wt<<<dim3(32),   256, 0, stream>>>(w02, w02t, 128, 64, 8192);
    cvt_xT<<<dim3(64, 7, 8), 256, 0, stream>>>(x, xht);

    // 3. branch 0 (MFMA) -> X0 logits
    branch0_mfma<<<dim3(7, 49, 8), 256, 0, stream>>>(
        subh, w01t, b01, w02t, b02, w03, b03, X0);

    // 4. conv branch (MFMA fp16) -> X1 logits
    conv1_mfma<<<dim3(7, 25, 8), 256, 0, stream>>>(subh, w1t, b1, Y1h);
    conv2_mfma<<<dim3(7, 98, 8), 256, 0, stream>>>(Y1h, w2t, b2, Y2h);
    conv3_h<<<dim3(151, 8), 256, 0, stream>>>(Y2h, w3, b3, X1);

    // 5. symmetrize + softmax both maps (x0.5 folded in)
    symsoftmax<<<dim3(8, 2), 1024, 0, stream>>>(X0, X1);

    // 6. Ph = (map0 + map1) * 512 as fp16
    combine_ph<<<dim3(1225), 256, 0, stream>>>(X0, X1, Ph);

    // 7. out[b] = Ph[b]/512 @ x[b]  (fp16 MFMA, fp32 accum)
    gemm_out<<<dim3(16, 4, 8), 256, 0, stream>>>(Ph, xht, (float*)d_out);
}

// Round 6
// 564.226 us; speedup vs baseline: 1.1813x; 1.1813x over previous
//
#include <hip/hip_runtime.h>
#include <cmath>

#define N_TOK 196
#define NPX   38416
#define CDIM  256

typedef _Float16 f16;
typedef __attribute__((ext_vector_type(8))) _Float16 half8;
typedef __attribute__((ext_vector_type(4))) float f32x4;

// ---------------------------------------------------------------------------
// Projection GEMM, split-K. M=1568, N=256, K=2048 split 8 ways. grid (4,25,8).
// ---------------------------------------------------------------------------
__global__ __launch_bounds__(256) void gemm_splitk(
    const float* __restrict__ A, const float* __restrict__ B,
    float* __restrict__ P)
{
    __shared__ float As[16][68];
    __shared__ float Bs[16][68];
    int tid = threadIdx.x;
    int tx = tid & 15, ty = tid >> 4;
    int m0 = blockIdx.y * 64, n0 = blockIdx.x * 64;
    int kz = blockIdx.z;
    float acc[4][4] = {};
    for (int k0 = kz * 256; k0 < kz * 256 + 256; k0 += 16) {
        __syncthreads();
        for (int e = tid; e < 1024; e += 256) {
            int m = e >> 4, kk = e & 15;
            int gm = m0 + m;
            As[kk][m] = (gm < 1568) ? A[(size_t)gm * 2048 + k0 + kk] : 0.f;
        }
        for (int e = tid; e < 1024; e += 256) {
            int kk = e >> 6, n = e & 63;
            Bs[kk][n] = B[(size_t)(k0 + kk) * 256 + n0 + n];
        }
        __syncthreads();
        #pragma unroll
        for (int kk = 0; kk < 16; ++kk) {
            float4 av = *(const float4*)&As[kk][ty * 4];
            float4 bv = *(const float4*)&Bs[kk][tx * 4];
            float a[4] = {av.x, av.y, av.z, av.w};
            float b[4] = {bv.x, bv.y, bv.z, bv.w};
            #pragma unroll
            for (int u = 0; u < 4; ++u)
                #pragma unroll
                for (int v = 0; v < 4; ++v) acc[u][v] += a[u] * b[v];
        }
    }
    float* Pz = P + (size_t)kz * 401408;
    #pragma unroll
    for (int u = 0; u < 4; ++u) {
        int gm = m0 + ty * 4 + u;
        if (gm >= 1568) continue;
        #pragma unroll
        for (int v = 0; v < 4; ++v) {
            int gn = n0 + tx * 4 + v;
            Pz[(size_t)gm * 256 + gn] = acc[u][v];
        }
    }
}

// sum 8 K-slices + bias -> fp16 sub
__global__ void reduce_subh(const float* __restrict__ P,
                            const float* __restrict__ bias,
                            f16* __restrict__ subh)
{
    int e = blockIdx.x * 256 + threadIdx.x;
    if (e >= 401408) return;
    float s = bias[e & 255];
    #pragma unroll
    for (int z = 0; z < 8; ++z) s += P[(size_t)z * 401408 + e];
    subh[e] = (f16)s;
}

// ---------------------------------------------------------------------------
// w [tap][Kc][D] fp32 -> wt [tap][D][Kc] fp16  (plain transpose, branch0)
// ---------------------------------------------------------------------------
__global__ void cvt_wt(const float* __restrict__ w, f16* __restrict__ wt,
                       int Kc, int D, int total)
{
    int e = blockIdx.x * 256 + threadIdx.x;
    if (e >= total) return;
    int td = Kc * D;
    int tap = e / td, r = e - tap * td;
    int c = r / D, d = r - c * D;
    wt[(size_t)(tap * D + d) * Kc + c] = (f16)w[e];
}

// ---------------------------------------------------------------------------
// w [tap][Kc][D] fp32 -> MFMA B-fragment-packed fp16:
// wf[(((tap*tiles + tile)*kch + k)*64 + lane)*8 + j], lane=(quad*16+l16),
// element = w[tap][k*32 + quad*8 + j][tile*16 + l16].
// Each lane's 16B is contiguous -> perfectly coalesced fragment loads.
// ---------------------------------------------------------------------------
__global__ void cvt_wfrag(const float* __restrict__ w, f16* __restrict__ wf,
                          int Kc, int D, int taps)
{
    int tiles = D >> 4, kch = Kc >> 5;
    int total = taps * tiles * kch * 64;
    int e = blockIdx.x * 256 + threadIdx.x;
    if (e >= total) return;
    int lane = e & 63;
    int rest = e >> 6;
    int k = rest % kch; rest /= kch;
    int tile = rest % tiles;
    int tap = rest / tiles;
    int l16 = lane & 15, quad = lane >> 4;
    const float* src = w + ((size_t)tap * Kc + k * 32 + quad * 8) * D + tile * 16 + l16;
    f16* dst = wf + (size_t)e * 8;
    #pragma unroll
    for (int j = 0; j < 8; ++j) dst[j] = (f16)src[(size_t)j * D];
}

// x [b][196][2048] fp32 -> xht [b][2048][200] fp16 (k-pad 200, zeros)
__global__ __launch_bounds__(256) void cvt_xT(const float* __restrict__ x,
                                              f16* __restrict__ xht)
{
    __shared__ float t[32][33];
    int b = blockIdx.z;
    int i0 = blockIdx.y * 32, n0 = blockIdx.x * 32;
    const float* xb = x + (size_t)b * 196 * 2048;
    for (int e = threadIdx.x; e < 1024; e += 256) {
        int r = e >> 5, c = e & 31;
        int gi = i0 + r;
        t[r][c] = (gi < 196) ? xb[(size_t)gi * 2048 + n0 + c] : 0.f;
    }
    __syncthreads();
    f16* xb2 = xht + (size_t)b * 2048 * 200;
    for (int e = threadIdx.x; e < 1024; e += 256) {
        int nl = e >> 5, il = e & 31;
        int gi = i0 + il, gn = n0 + nl;
        if (gi < 200) xb2[(size_t)gn * 200 + gi] = (f16)t[il][nl];
    }
}

// ---------------------------------------------------------------------------
// Conv1 v4: barrier-free K-loop, frag-packed B, dedup'd pair construction.
// Block 256px (8i x 32j) x 128d, 4 waves; wave = 128px (4i) x 64d.
// Loop (c0, dj, r): each si[r]*sj[dj] product feeds all (i,di) with i+di=r
// (halves VALU vs tap-loop). B loads: coalesced 1KB fragment reads (L2-hot).
// grid (7, 25, 8).
// ---------------------------------------------------------------------------
__global__ __launch_bounds__(256, 2) void conv1_mfma(
    const f16* __restrict__ sub_h,   // [8][196][256]
    const f16* __restrict__ w1f,     // frag-packed [9][8][8][64][8]
    const float* __restrict__ b1,    // [128]
    f16* __restrict__ Y1h)           // [8][196][196][128]
{
    __shared__ f16 sh[17408];        // 34816 B
    f16* SJ = sh;                    // [34][264] rows j0-1..j0+32
    f16* SI = sh + 8976;             // [10][264] rows i0-1..i0+8
    f16* OT = sh;                    // epilogue [128][136] (aliases SJ/SI)

    int b = blockIdx.z;
    int i0 = blockIdx.y * 8, j0 = blockIdx.x * 32;
    int tid = threadIdx.x;
    const f16* subB = sub_h + (size_t)b * N_TOK * CDIM;

    uint4 zz = make_uint4(0, 0, 0, 0);
    for (int e = tid; e < 1088; e += 256) {       // SJ
        int r = e >> 5, q = e & 31;
        int gj = j0 - 1 + r;
        uint4 v = zz;
        if (gj >= 0 && gj < N_TOK) v = *(const uint4*)(subB + gj * CDIM + q * 8);
        *(uint4*)(SJ + r * 264 + q * 8) = v;
    }
    for (int e = tid; e < 320; e += 256) {        // SI
        int r = e >> 5, q = e & 31;
        int gi = i0 - 1 + r;
        uint4 v = zz;
        if (gi >= 0 && gi < N_TOK) v = *(const uint4*)(subB + gi * CDIM + q * 8);
        *(uint4*)(SI + r * 264 + q * 8) = v;
    }
    __syncthreads();

    int wave = tid >> 6, lane = tid & 63;
    int quad = lane >> 4, l16 = lane & 15;
    int p  = wave >> 1;          // px half: i base = p*4
    int dh = wave & 1;           // d half: d0 = dh*64
    int d0 = dh * 64;

    float bias_r[4];
    #pragma unroll
    for (int n = 0; n < 4; ++n) bias_r[n] = b1[d0 + n * 16 + l16];

    // frag strides (halfs): lane 8, k 512, tile 4096, tap 32768
    const f16* wbase = w1f + (size_t)lane * 8 + (size_t)dh * 4 * 4096;

    f32x4 zero = {0.f, 0.f, 0.f, 0.f};
    f32x4 acc[8][4];
    #pragma unroll
    for (int m = 0; m < 8; ++m)
        #pragma unroll
        for (int n = 0; n < 4; ++n) acc[m][n] = zero;

    for (int k = 0; k < 8; ++k) {
        int c0 = k * 32;
        half8 si[6];
        #pragma unroll
        for (int r = 0; r < 6; ++r)
            si[r] = *(const half8*)(SI + (p * 4 + r) * 264 + c0 + quad * 8);
        half8 sj[2][3];
        #pragma unroll
        for (int jf = 0; jf < 2; ++jf)
            #pragma unroll
            for (int dd = 0; dd < 3; ++dd)
                sj[jf][dd] = *(const half8*)(SJ + (jf * 16 + l16 + dd) * 264 + c0 + quad * 8);

        #pragma unroll
        for (int dj = 0; dj < 3; ++dj) {
            half8 bf[3][4];
            #pragma unroll
            for (int di = 0; di < 3; ++di)
                #pragma unroll
                for (int n = 0; n < 4; ++n)
                    bf[di][n] = *(const half8*)(wbase + (size_t)(di * 3 + dj) * 32768
                                                + n * 4096 + k * 512);
            #pragma unroll
            for (int r = 0; r < 6; ++r) {
                half8 a0 = si[r] * sj[0][dj];
                half8 a1 = si[r] * sj[1][dj];
                #pragma unroll
                for (int di = 0; di < 3; ++di) {
                    int i = r - di;
                    if (i < 0 || i > 3) continue;
                    #pragma unroll
                    for (int n = 0; n < 4; ++n) {
                        acc[i * 2 + 0][n] = __builtin_amdgcn_mfma_f32_16x16x32_f16(
                            a0, bf[di][n], acc[i * 2 + 0][n], 0, 0, 0);
                        acc[i * 2 + 1][n] = __builtin_amdgcn_mfma_f32_16x16x32_f16(
                            a1, bf[di][n], acc[i * 2 + 1][n], 0, 0, 0);
                    }
                }
            }
        }
    }

    // epilogue: two px-half phases through OT (aliases SJ/SI)
    __syncthreads();
    f16* Yb = Y1h + (size_t)b * NPX * 128;
    #pragma unroll
    for (int ph = 0; ph < 2; ++ph) {
        if (p == ph) {
            #pragma unroll
            for (int i = 0; i < 4; ++i)
                #pragma unroll
                for (int jf = 0; jf < 2; ++jf) {
                    int m = i * 2 + jf;
                    #pragma unroll
                    for (int n = 0; n < 4; ++n) {
                        int dl = d0 + n * 16 + l16;
                        #pragma unroll
                        for (int r = 0; r < 4; ++r) {
                            int pxl = i * 32 + jf * 16 + quad * 4 + r;
                            OT[pxl * 136 + dl] = (f16)fmaxf(acc[m][n][r] + bias_r[n], 0.f);
                        }
                    }
                }
        }
        __syncthreads();
        for (int e = tid; e < 2048; e += 256) {
            int pxl = e >> 4, q = e & 15;
            int gi = i0 + ph * 4 + (pxl >> 5), gj = j0 + (pxl & 31);
            if (gi < N_TOK && gj < N_TOK)
                *(uint4*)(Yb + ((size_t)gi * N_TOK + gj) * 128 + q * 8) =
                    *(const uint4*)(OT + pxl * 136 + q * 8);
        }
        __syncthreads();
    }
}

// ---------------------------------------------------------------------------
// Conv2 v2: 3x3 dil (1,2), 128->64, frag-packed B, barrier-free K-loop.
// Tile 64px (2i x 32j) x 64d. grid (7, 98, 8).
// ---------------------------------------------------------------------------
__global__ __launch_bounds__(256, 2) void conv2_mfma(
    const f16* __restrict__ Y1h, const f16* __restrict__ w2f,
    const float* __restrict__ b2, f16* __restrict__ Y2h)
{
    __shared__ f16 sh[19584];
    f16* Ys = sh;                    // [4][36][136]
    f16* OT = sh;                    // epilogue [64][72]

    int b = blockIdx.z;
    int i0 = blockIdx.y * 2, j0 = blockIdx.x * 32;
    int tid = threadIdx.x;
    const f16* Yb = Y1h + (size_t)b * NPX * 128;

    uint4 zz = make_uint4(0, 0, 0, 0);
    for (int e = tid; e < 2304; e += 256) {
        int ir = e / 576, rem = e - ir * 576;
        int jq = rem >> 4, q = rem & 15;
        int gi = i0 - 1 + ir, gj = j0 - 2 + jq;
        uint4 v = zz;
        if (gi >= 0 && gi < N_TOK && gj >= 0 && gj < N_TOK)
            v = *(const uint4*)(Yb + ((size_t)gi * N_TOK + gj) * 128 + q * 8);
        *(uint4*)(Ys + (ir * 36 + jq) * 136 + q * 8) = v;
    }
    __syncthreads();

    int wave = tid >> 6, lane = tid & 63;
    int quad = lane >> 4, l16 = lane & 15;
    int ii = wave >> 1, jb = (wave & 1) * 16;

    // frag strides (halfs): lane 8, k 512, tile 2048, tap 8192
    const f16* wbase = w2f + (size_t)lane * 8;

    f32x4 zero = {0.f, 0.f, 0.f, 0.f};
    f32x4 acc[4] = {zero, zero, zero, zero};

    #pragma unroll
    for (int tap = 0; tap < 9; ++tap) {
        int di = tap / 3 - 1, dj2 = (tap % 3 - 1) * 2;
        #pragma unroll
        for (int k = 0; k < 4; ++k) {
            int c0 = k * 32;
            half8 a = *(const half8*)(Ys + ((ii + di + 1) * 36 + jb + l16 + dj2 + 2) * 136
                                      + c0 + quad * 8);
            #pragma unroll
            for (int n = 0; n < 4; ++n) {
                half8 bf = *(const half8*)(wbase + (size_t)tap * 8192 + n * 2048 + k * 512);
                acc[n] = __builtin_amdgcn_mfma_f32_16x16x32_f16(a, bf, acc[n], 0, 0, 0);
            }
        }
    }
    __syncthreads();
    #pragma unroll
    for (int n = 0; n < 4; ++n) {
        int d = n * 16 + l16;
        float bias = b2[d];
        #pragma unroll
        for (int r = 0; r < 4; ++r) {
            int px = ii * 32 + jb + quad * 4 + r;
            OT[px * 72 + d] = (f16)fmaxf(acc[n][r] + bias, 0.f);
        }
    }
    __syncthreads();
    f16* Zb = Y2h + (size_t)b * NPX * 64;
    for (int e = tid; e < 512; e += 256) {
        int px = e >> 3, q = e & 7;
        int i = i0 + (px >> 5), j = j0 + (px & 31);
        if (j < N_TOK)
            *(uint4*)(Zb + ((size_t)i * N_TOK + j) * 64 + q * 8) =
                *(const uint4*)(OT + px * 72 + q * 8);
    }
}

// ---------------------------------------------------------------------------
// Conv3: 3x3 dil (1,4), 64->1, fp16 input, fp32 accumulate -> X1 logits.
// ---------------------------------------------------------------------------
__global__ __launch_bounds__(256) void conv3_h(
    const f16* __restrict__ Y2h, const float* __restrict__ w3,
    const float* __restrict__ b3, float* __restrict__ X1)
{
    __shared__ float w[576];
    int b = blockIdx.y;
    const f16* Yb = Y2h + (size_t)b * NPX * 64;
    for (int e = threadIdx.x; e < 576; e += 256) w[e] = w3[e];
    __syncthreads();
    int px = blockIdx.x * 256 + threadIdx.x;
    if (px >= NPX) return;
    int i = px / 196, j = px - i * 196;
    float s = b3[0];
    for (int tap = 0; tap < 9; ++tap) {
        int gi = i + tap / 3 - 1, gj = j + (tap % 3 - 1) * 4;
        if (gi < 0 || gi >= N_TOK || gj < 0 || gj >= N_TOK) continue;
        const half8* src = (const half8*)(Yb + ((size_t)gi * N_TOK + gj) * 64);
        const float* wt = w + tap * 64;
        #pragma unroll
        for (int q = 0; q < 8; ++q) {
            half8 h = src[q];
            #pragma unroll
            for (int e = 0; e < 8; ++e) s += (float)h[e] * wt[q * 8 + e];
        }
    }
    X1[(size_t)b * NPX + px] = fmaxf(s, 0.f);
}

// ---------------------------------------------------------------------------
// Branch 0 MFMA: pair -> 1x1 stack 256->128->64->1, all in one block.
// ---------------------------------------------------------------------------
__global__ __launch_bounds__(256, 2) void branch0_mfma(
    const f16* __restrict__ sub_h,
    const f16* __restrict__ w01t,    // [128][256]
    const float* __restrict__ b01,
    const f16* __restrict__ w02t,    // [64][128]
    const float* __restrict__ b02,
    const float* __restrict__ w03, const float* __restrict__ b03,
    float* __restrict__ X0)
{
    __shared__ f16 sh[32000];
    __shared__ float W3s[64];
    f16* SJ = sh;            // [32][264]
    f16* SI = sh + 8448;     // [4][256]
    f16* BW = sh + 9472;     // [128][40]
    f16* H1 = sh + 14592;    // [128][136]
    f16* H2 = sh;            // [128][72] (aliases SJ/SI)

    int b = blockIdx.z;
    int i0 = blockIdx.y * 4, j0 = blockIdx.x * 32;
    int tid = threadIdx.x;
    const f16* subB = sub_h + (size_t)b * N_TOK * CDIM;

    uint4 zz = make_uint4(0, 0, 0, 0);
    for (int e = tid; e < 1024; e += 256) {
        int r = e >> 5, q = e & 31;
        int gj = j0 + r;
        uint4 v = zz;
        if (gj < N_TOK) v = *(const uint4*)(subB + gj * CDIM + q * 8);
        *(uint4*)(SJ + r * 264 + q * 8) = v;
    }
    if (tid < 128) {
        int r = tid >> 5, q = tid & 31;
        int gi = i0 + r;
        uint4 v = zz;
        if (gi < N_TOK) v = *(const uint4*)(subB + gi * CDIM + q * 8);
        *(uint4*)(SI + r * 256 + q * 8) = v;
    }
    if (tid < 64) W3s[tid] = w03[tid];

    int wave = tid >> 6, lane = tid & 63;
    int quad = lane >> 4, l16 = lane & 15;
    int ii = wave;

    f32x4 zero = {0.f, 0.f, 0.f, 0.f};
    f32x4 acc[2][8];
    #pragma unroll
    for (int t = 0; t < 2; ++t)
        #pragma unroll
        for (int n = 0; n < 8; ++n) acc[t][n] = zero;

    for (int c0 = 0; c0 < 256; c0 += 32) {
        __syncthreads();
        for (int e = tid; e < 512; e += 256) {
            int d = e >> 2, q = e & 3;
            *(uint4*)(BW + d * 40 + q * 8) =
                *(const uint4*)(w01t + (size_t)d * 256 + c0 + q * 8);
        }
        __syncthreads();
        half8 sib = *(const half8*)(SI + ii * 256 + c0 + quad * 8);
        half8 a0 = sib * *(const half8*)(SJ + l16 * 264 + c0 + quad * 8);
        half8 a1 = sib * *(const half8*)(SJ + (l16 + 16) * 264 + c0 + quad * 8);
        #pragma unroll
        for (int n = 0; n < 8; ++n) {
            half8 bf = *(const half8*)(BW + (n * 16 + l16) * 40 + quad * 8);
            acc[0][n] = __builtin_amdgcn_mfma_f32_16x16x32_f16(a0, bf, acc[0][n], 0, 0, 0);
            acc[1][n] = __builtin_amdgcn_mfma_f32_16x16x32_f16(a1, bf, acc[1][n], 0, 0, 0);
        }
    }
    #pragma unroll
    for (int t = 0; t < 2; ++t)
        #pragma unroll
        for (int n = 0; n < 8; ++n) {
            int d = n * 16 + l16;
            float bias = b01[d];
            #pragma unroll
            for (int r = 0; r < 4; ++r) {
                int px = ii * 32 + t * 16 + quad * 4 + r;
                H1[px * 136 + d] = (f16)fmaxf(acc[t][n][r] + bias, 0.f);
            }
        }

    f32x4 acc2[2][4];
    #pragma unroll
    for (int t = 0; t < 2; ++t)
        #pragma unroll
        for (int n = 0; n < 4; ++n) acc2[t][n] = zero;

    for (int c0 = 0; c0 < 128; c0 += 32) {
        __syncthreads();
        {
            int d = tid >> 2, q = tid & 3;
            if (d < 64)
                *(uint4*)(BW + d * 40 + q * 8) =
                    *(const uint4*)(w02t + (size_t)d * 128 + c0 + q * 8);
        }
        __syncthreads();
        half8 a0 = *(const half8*)(H1 + (ii * 32 + l16) * 136 + c0 + quad * 8);
        half8 a1 = *(const half8*)(H1 + (ii * 32 + 16 + l16) * 136 + c0 + quad * 8);
        #pragma unroll
        for (int n = 0; n < 4; ++n) {
            half8 bf = *(const half8*)(BW + (n * 16 + l16) * 40 + quad * 8);
            acc2[0][n] = __builtin_amdgcn_mfma_f32_16x16x32_f16(a0, bf, acc2[0][n], 0, 0, 0);
            acc2[1][n] = __builtin_amdgcn_mfma_f32_16x16x32_f16(a1, bf, acc2[1][n], 0, 0, 0);
        }
    }
    #pragma unroll
    for (int t = 0; t < 2; ++t)
        #pragma unroll
        for (int n = 0; n < 4; ++n) {
            int e = n * 16 + l16;
            float bias = b02[e];
            #pragma unroll
            for (int r = 0; r < 4; ++r) {
                int px = ii * 32 + t * 16 + quad * 4 + r;
                H2[px * 72 + e] = (f16)fmaxf(acc2[t][n][r] + bias, 0.f);
            }
        }
    __syncthreads();
    if (tid < 128) {
        int px = tid;
        float s = b03[0];
        const f16* h = H2 + px * 72;
        #pragma unroll 8
        for (int c = 0; c < 64; ++c) s += (float)h[c] * W3s[c];
        int i = i0 + (px >> 5), j = j0 + (px & 31);
        if (j < N_TOK)
            X0[(size_t)b * NPX + i * N_TOK + j] = fmaxf(s, 0.f);
    }
}

// ---------------------------------------------------------------------------
// Symmetrize + softmax over 38416 logits, /2 folded in.
// ---------------------------------------------------------------------------
__global__ __launch_bounds__(1024) void symsoftmax(float* __restrict__ X0,
                                                   float* __restrict__ X1)
{
    __shared__ float red[32];
    __shared__ float red2[32];
    float* X = (blockIdx.y ? X1 : X0) + (long long)blockIdx.x * NPX;
    int tid = threadIdx.x;
    float v[38];
    float mx = -3.0e38f;
    #pragma unroll
    for (int p = 0; p < 38; ++p) {
        int e = tid + p * 1024;
        if (e < NPX) {
            int i = e / 196, j = e - i * 196;
            float t = X[e] + X[j * 196 + i];
            v[p] = t;
            mx = fmaxf(mx, t);
        } else v[p] = -3.0e38f;
    }
    #pragma unroll
    for (int off = 32; off > 0; off >>= 1) mx = fmaxf(mx, __shfl_xor(mx, off));
    if ((tid & 63) == 0) red[tid >> 6] = mx;
    __syncthreads();
    if (tid < 64) {
        float m = (tid < 16) ? red[tid] : -3.0e38f;
        #pragma unroll
        for (int off = 8; off > 0; off >>= 1) m = fmaxf(m, __shfl_xor(m, off));
        if (tid == 0) red[0] = m;
    }
    __syncthreads();
    mx = red[0];
    float s = 0.f;
    #pragma unroll
    for (int p = 0; p < 38; ++p) {
        int e = tid + p * 1024;
        float ex = (e < NPX) ? expf(v[p] - mx) : 0.f;
        v[p] = ex;
        s += ex;
    }
    #pragma unroll
    for (int off = 32; off > 0; off >>= 1) s += __shfl_xor(s, off);
    if ((tid & 63) == 0) red2[tid >> 6] = s;
    __syncthreads();
    if (tid < 64) {
        float m = (tid < 16) ? red2[tid] : 0.f;
        #pragma unroll
        for (int off = 8; off > 0; off >>= 1) m += __shfl_xor(m, off);
        if (tid == 0) red2[0] = m;
    }
    __syncthreads();
    float scale = 0.5f / red2[0];
    #pragma unroll
    for (int p = 0; p < 38; ++p) {
        int e = tid + p * 1024;
        if (e < NPX) X[e] = v[p] * scale;
    }
}

// Ph[b][i][200] = fp16( (X0+X1) * 512 ), row-padded with zeros
__global__ void combine_ph(const float* __restrict__ X0,
                           const float* __restrict__ X1,
                           f16* __restrict__ Ph)
{
    int e = blockIdx.x * 256 + threadIdx.x;
    if (e >= 8 * 196 * 200) return;
    int j = e % 200;
    int row = e / 200;
    f16 v = (f16)0.f;
    if (j < 196) {
        int src = row * 196 + j;
        v = (f16)((X0[src] + X1[src]) * 512.0f);
    }
    Ph[e] = v;
}

// ---------------------------------------------------------------------------
// out[b] = (Ph[b]/512) @ x[b] via fp16 MFMA. grid (16, 4, 8).
// ---------------------------------------------------------------------------
__global__ __launch_bounds__(256, 2) void gemm_out(
    const f16* __restrict__ Ph, const f16* __restrict__ xht,
    float* __restrict__ out)
{
    __shared__ f16 As[64 * 72];
    __shared__ f16 Bs[128 * 72];
    int b = blockIdx.z;
    int n0 = blockIdx.x * 128, m0 = blockIdx.y * 64;
    int tid = threadIdx.x;
    const f16* Pb = Ph + (size_t)b * 196 * 200;
    const f16* xb = xht + (size_t)b * 2048 * 200;

    int wave = tid >> 6, lane = tid & 63;
    int quad = lane >> 4, l16 = lane & 15;

    f32x4 zero = {0.f, 0.f, 0.f, 0.f};
    f32x4 acc[8];
    #pragma unroll
    for (int n = 0; n < 8; ++n) acc[n] = zero;

    uint4 zz = make_uint4(0, 0, 0, 0);
    for (int k0 = 0; k0 < 256; k0 += 64) {
        __syncthreads();
        for (int e = tid; e < 512; e += 256) {
            int r = e >> 3, q = e & 7;
            int gm = m0 + r, k = k0 + q * 8;
            uint4 v = zz;
            if (gm < 196 && k < 200) v = *(const uint4*)(Pb + (size_t)gm * 200 + k);
            *(uint4*)(As + r * 72 + q * 8) = v;
        }
        for (int e = tid; e < 1024; e += 256) {
            int r = e >> 3, q = e & 7;
            int k = k0 + q * 8;
            uint4 v = zz;
            if (k < 200) v = *(const uint4*)(xb + (size_t)(n0 + r) * 200 + k);
            *(uint4*)(Bs + r * 72 + q * 8) = v;
        }
        __syncthreads();
        #pragma unroll
        for (int ks = 0; ks < 2; ++ks) {
            half8 a = *(const half8*)(As + (wave * 16 + l16) * 72 + ks * 32 + quad * 8);
            #pragma unroll
            for (int n = 0; n < 8; ++n) {
                half8 bf = *(const half8*)(Bs + (n * 16 + l16) * 72 + ks * 32 + quad * 8);
                acc[n] = __builtin_amdgcn_mfma_f32_16x16x32_f16(a, bf, acc[n], 0, 0, 0);
            }
        }
    }
    int m_base = m0 + wave * 16 + quad * 4;
    float* ob = out + (size_t)b * 196 * 2048;
    #pragma unroll
    for (int n = 0; n < 8; ++n) {
        int gn = n0 + n * 16 + l16;
        #pragma unroll
        for (int r = 0; r < 4; ++r) {
            int gm = m_base + r;
            if (gm < 196) ob[(size_t)gm * 2048 + gn] = acc[n][r] * (1.0f / 512.0f);
        }
    }
}

// ---------------------------------------------------------------------------
extern "C" void kernel_launch(void* const* d_in, const int* in_sizes, int n_in,
                              void* d_out, int out_size, void* d_ws, size_t ws_size,
                              hipStream_t stream)
{
    (void)in_sizes; (void)n_in; (void)out_size; (void)ws_size;
    const float* x     = (const float*)d_in[0];
    const float* w_prj = (const float*)d_in[1];
    const float* b_prj = (const float*)d_in[2];
    const float* w01   = (const float*)d_in[3];
    const float* b01   = (const float*)d_in[4];
    const float* w02   = (const float*)d_in[5];
    const float* b02   = (const float*)d_in[6];
    const float* w03   = (const float*)d_in[7];
    const float* b03   = (const float*)d_in[8];
    const float* w1    = (const float*)d_in[9];
    const float* b1    = (const float*)d_in[10];
    const float* w2    = (const float*)d_in[11];
    const float* b2    = (const float*)d_in[12];
    const float* w3    = (const float*)d_in[13];
    const float* b3    = (const float*)d_in[14];

    char* W = (char*)d_ws;
    float* part = (float*)(W + 0);          // 8*401408 f = 12.85 MB
    float* X0   = (float*)(W + 12845056);   // 307328 f
    float* X1   = (float*)(W + 14074368);   // 307328 f
    f16*   subh = (f16*)(W + 15303680);     // 401408 h
    f16*   w1f  = (f16*)(W + 16106496);     // 294912 h (frag-packed)
    f16*   w2f  = (f16*)(W + 16696320);     // 73728 h (frag-packed)
    f16*   w01t = (f16*)(W + 16843776);     // 32768 h
    f16*   w02t = (f16*)(W + 16909312);     // 8192 h
    f16*   Ph   = (f16*)(W + 16925696);     // 8*196*200 h
    f16*   xht  = (f16*)(W + 17552896);     // 8*2048*200 h
    f16*   Y1h  = (f16*)(W + 24106496);     // 8*38416*128 h = 78.7 MB
    f16*   Y2h  = (f16*)(W + 102782464);    // 8*38416*64 h  = 39.3 MB

    // 1. projection: split-K gemm -> partials -> reduce -> subh (fp16)
    gemm_splitk<<<dim3(4, 25, 8), 256, 0, stream>>>(x, w_prj, part);
    reduce_subh<<<dim3(1568), 256, 0, stream>>>(part, b_prj, subh);

    // 2. weight conversions (frag-packed for conv1/conv2) + x transpose
    cvt_wfrag<<<dim3(144), 256, 0, stream>>>(w1, w1f, 256, 128, 9);
    cvt_wfrag<<<dim3(36),  256, 0, stream>>>(w2, w2f, 128, 64, 9);
    cvt_wt<<<dim3(128),  256, 0, stream>>>(w01, w01t, 256, 128, 32768);
    cvt_wt<<<dim3(32),   256, 0, stream>>>(w02, w02t, 128, 64, 8192);
    cvt_xT<<<dim3(64, 7, 8), 256, 0, stream>>>(x, xht);

    // 3. branch 0 (MFMA) -> X0 logits
    branch0_mfma<<<dim3(7, 49, 8), 256, 0, stream>>>(
        subh, w01t, b01, w02t, b02, w03, b03, X0);

    // 4. conv branch (MFMA fp16) -> X1 logits
    conv1_mfma<<<dim3(7, 25, 8), 256, 0, stream>>>(subh, w1f, b1, Y1h);
    conv2_mfma<<<dim3(7, 98, 8), 256, 0, stream>>>(Y1h, w2f, b2, Y2h);
    conv3_h<<<dim3(151, 8), 256, 0, stream>>>(Y2h, w3, b3, X1);

    // 5. symmetrize + softmax both maps (x0.5 folded in)
    symsoftmax<<<dim3(8, 2), 1024, 0, stream>>>(X0, X1);

    // 6. Ph = (map0 + map1) * 512 as fp16
    combine_ph<<<dim3(1225), 256, 0, stream>>>(X0, X1, Ph);

    // 7. out[b] = Ph[b]/512 @ x[b]  (fp16 MFMA, fp32 accum)
    gemm_out<<<dim3(16, 4, 8), 256, 0, stream>>>(Ph, xht, (float*)d_out);
}